// Round 7
// baseline (414.935 us; speedup 1.0000x reference)
//
#include <hip/hip_runtime.h>

// SNN: 2-layer LIF, T=4096, B=1024, 6->10->27.
// Round 7: R5's 3-wave pipeline (3 waves/SIMD) + overhead fixes:
//  - barrier interval 128 steps (34 barriers vs 66)
//  - runtime group/round loops, compact bodies (~3-4KB hot code, I$-resident)
//  - cur2Buf laid out [t][28]: scatter writes <=2-way banks (free)
//  - gather wave processes 16 steps per batch: broadcast uint4 mask reads,
//    16 table reads issued together, adds/stores after (latency amortized)
// Roles per block (block = one batch element, 192 threads):
//  wave 0: cur1 precompute + mem1 chain + publish masks (interval ki)
//  wave 1: step-parallel table gather -> cur2Buf (interval ki-1)
//  wave 2: pure mem2 chain (interval ki-2)
// Arithmetic identical to rounds 1-6 (absmax 0.0).

#define T_STEPS 4096
#define BETA 0.9f
#define THRESH 1.0f
#define IV 128                 // steps per barrier interval
#define NI (T_STEPS / IV)      // 32 intervals
#define NPASS 2                // 64-step passes per interval (lane = step-in-pass)

__global__ __launch_bounds__(192, 1) void snn_kernel(
    const float* __restrict__ x,   // [B][6][T]
    const float* __restrict__ W1,  // [10][6]
    const float* __restrict__ b1,  // [10]
    const float* __restrict__ W2,  // [27][10]
    const float* __restrict__ b2,  // [27]
    float* __restrict__ out)       // [B][27]
{
    __shared__ float tabLo[32 * 28];        // [m][j]: b2[j] + sum_{i<5} bit_i(m)*W2[j][i]
    __shared__ float tabHi[32 * 28];        // [m][j]: sum_{i<5} bit_i(m)*W2[j][5+i]
    __shared__ float curBuf[10 * 68];       // wave-0 private [neuron][t-in-pass]
    __shared__ unsigned maskBuf[2][IV];     // [parity][t-in-interval]
    __shared__ float cur2Buf[2][IV * 28];   // [parity][t][neuron] -- <=2-way write banks

    const int tid = threadIdx.x;
    const int wid = tid >> 6;
    const int l   = tid & 63;
    const int b   = blockIdx.x;

    // ---- layer-2 lookup tables (identical construction to rounds 1-6) ----
    if (tid < 32) {
        for (int j = 0; j < 27; ++j) {
            float slo = b2[j];
            float shi = 0.0f;
            #pragma unroll
            for (int i = 0; i < 5; ++i) {
                if (tid & (1 << i)) {
                    slo += W2[j * 10 + i];
                    shi += W2[j * 10 + 5 + i];
                }
            }
            tabLo[tid * 28 + j] = slo;
            tabHi[tid * 28 + j] = shi;
        }
    }

    // ---- wave-0 state ----
    float w1r[60], b1r[10];
    float xv[6], xn[6];
    float mem1 = 0.0f;
    bool  sp1 = false;
    const int ri = (l < 10) ? l : 9;
    const float* cp = &curBuf[ri * 68];
    const float* xb = x + (size_t)b * 6 * T_STEPS;

    if (wid == 0) {
        #pragma unroll
        for (int i = 0; i < 10; ++i) {
            b1r[i] = b1[i];
            #pragma unroll
            for (int c = 0; c < 6; ++c) w1r[i * 6 + c] = W1[i * 6 + c];
        }
        #pragma unroll
        for (int c = 0; c < 6; ++c) xv[c] = xb[c * T_STEPS + l];   // pass 0
    }

    // ---- wave-1 (gather) state: lane = (half gh, neuron gj) ----
    const int gh  = l >> 5;
    const int gjr = l & 31;
    const int gj  = (gjr < 27) ? gjr : 26;   // dup lanes write identical values
    const bool hsel = (gh != 0);

    // ---- wave-2 state ----
    float mem2 = 0.0f;
    bool  sp2 = false;
    const int jc = (l < 27) ? l : 26;

    __syncthreads();

    #pragma unroll 1
    for (int ki = 0; ki <= NI + 1; ++ki) {
        // ========== wave 0: layer 1, interval ki ==========
        if (wid == 0 && ki < NI) {
            #pragma unroll 1
            for (int c = 0; c < NPASS; ++c) {
                const int p = ki * NPASS + c;     // global 64-step pass index
                // prefetch next pass's x
                if (p + 1 < NI * NPASS) {
                    #pragma unroll
                    for (int ch = 0; ch < 6; ++ch)
                        xn[ch] = xb[ch * T_STEPS + (p + 1) * 64 + l];
                }
                // t-parallel cur1 for this pass (lane = step), same fma order
                #pragma unroll
                for (int i = 0; i < 10; ++i) {
                    float acc = xv[0] * w1r[i * 6 + 0];
                    acc = fmaf(xv[1], w1r[i * 6 + 1], acc);
                    acc = fmaf(xv[2], w1r[i * 6 + 2], acc);
                    acc = fmaf(xv[3], w1r[i * 6 + 3], acc);
                    acc = fmaf(xv[4], w1r[i * 6 + 4], acc);
                    acc = fmaf(xv[5], w1r[i * 6 + 5], acc);
                    curBuf[i * 68 + l] = acc + b1r[i];
                }

                // sequential mem1 chain, 64 steps, runtime group loop
                unsigned vmask = 0u;
                float c1v[8], c1n[8];
                {
                    float4 q0 = *(const float4*)(cp + 0);
                    float4 q1 = *(const float4*)(cp + 4);
                    c1v[0] = q0.x; c1v[1] = q0.y; c1v[2] = q0.z; c1v[3] = q0.w;
                    c1v[4] = q1.x; c1v[5] = q1.y; c1v[6] = q1.z; c1v[7] = q1.w;
                }
                #pragma unroll 1
                for (int g = 0; g < 8; ++g) {
                    if (g < 7) {   // prefetch next group's currents
                        float4 q0 = *(const float4*)(cp + (g + 1) * 8);
                        float4 q1 = *(const float4*)(cp + (g + 1) * 8 + 4);
                        c1n[0] = q0.x; c1n[1] = q0.y; c1n[2] = q0.z; c1n[3] = q0.w;
                        c1n[4] = q1.x; c1n[5] = q1.y; c1n[6] = q1.z; c1n[7] = q1.w;
                    }
                    const int lg = l - g * 8;     // lane-vs-step compare base
                    #pragma unroll
                    for (int s = 0; s < 8; ++s) {
                        float t1 = fmaf(BETA, mem1, c1v[s]);
                        mem1 = sp1 ? (t1 - THRESH) : t1;       // == t1 - rst*THRESH
                        sp1 = mem1 > THRESH;
                        unsigned m = (unsigned)__ballot(sp1);
                        vmask = (lg == s) ? m : vmask;         // lane-select capture
                    }
                    if (g < 7) {
                        #pragma unroll
                        for (int s = 0; s < 8; ++s) c1v[s] = c1n[s];
                    }
                }
                maskBuf[ki & 1][c * 64 + l] = vmask;

                if (p + 1 < NI * NPASS) {
                    #pragma unroll
                    for (int ch = 0; ch < 6; ++ch) xv[ch] = xn[ch];
                }
            }
        }

        // ========== wave 1: step-parallel gather, interval ki-1 ==========
        if (wid == 1 && ki >= 1 && ki <= NI) {
            const int par = (ki - 1) & 1;
            const unsigned* mrow = maskBuf[par];
            float* crow = cur2Buf[par];

            #pragma unroll 1
            for (int bq = 0; bq < 8; ++bq) {      // 16 steps per batch
                // 16 masks via 4 broadcast uint4 reads
                uint4 u0 = *(const uint4*)(mrow + 16 * bq + 0);
                uint4 u1 = *(const uint4*)(mrow + 16 * bq + 4);
                uint4 u2 = *(const uint4*)(mrow + 16 * bq + 8);
                uint4 u3 = *(const uint4*)(mrow + 16 * bq + 12);
                unsigned me[8];                    // this lane's 8 masks (parity gh)
                me[0] = hsel ? u0.y : u0.x;  me[1] = hsel ? u0.w : u0.z;
                me[2] = hsel ? u1.y : u1.x;  me[3] = hsel ? u1.w : u1.z;
                me[4] = hsel ? u2.y : u2.x;  me[5] = hsel ? u2.w : u2.z;
                me[6] = hsel ? u3.y : u3.x;  me[7] = hsel ? u3.w : u3.z;

                float tl[8], th[8];
                #pragma unroll
                for (int r = 0; r < 8; ++r) {      // issue all 16 table reads
                    unsigned rl = (me[r] & 31u) * 28u;
                    unsigned rh = ((me[r] >> 5) & 31u) * 28u;
                    tl[r] = tabLo[rl + gj];
                    th[r] = tabHi[rh + gj];
                }
                #pragma unroll
                for (int r = 0; r < 8; ++r) {      // cur2 incl. b2 -> [t][28]
                    crow[(16 * bq + 2 * r + gh) * 28 + gj] = tl[r] + th[r];
                }
            }
        }

        // ========== wave 2: mem2 chain, interval ki-2 ==========
        if (wid == 2 && ki >= 2) {
            const int par = ki & 1;                // == (ki-2)&1
            const float* c2p = &cur2Buf[par][jc];
            float c2v[8], c2n[8];
            #pragma unroll
            for (int s = 0; s < 8; ++s) c2v[s] = c2p[s * 28];
            #pragma unroll 1
            for (int g = 0; g < 16; ++g) {         // 128 steps, 16 groups
                if (g < 15) {
                    #pragma unroll
                    for (int s = 0; s < 8; ++s) c2n[s] = c2p[((g + 1) * 8 + s) * 28];
                }
                #pragma unroll
                for (int s = 0; s < 8; ++s) {
                    float t2 = fmaf(BETA, mem2, c2v[s]);
                    mem2 = sp2 ? (t2 - THRESH) : t2;
                    sp2 = mem2 > THRESH;
                }
                if (g < 15) {
                    #pragma unroll
                    for (int s = 0; s < 8; ++s) c2v[s] = c2n[s];
                }
            }
        }

        __syncthreads();   // uniform: all 3 waves, every iteration
    }

    if (wid == 2 && l < 27) {
        out[b * 27 + l] = sp2 ? 1.0f : 0.0f;
    }
}

extern "C" void kernel_launch(void* const* d_in, const int* in_sizes, int n_in,
                              void* d_out, int out_size, void* d_ws, size_t ws_size,
                              hipStream_t stream) {
    const float* x  = (const float*)d_in[0];
    const float* W1 = (const float*)d_in[1];
    const float* b1 = (const float*)d_in[2];
    const float* W2 = (const float*)d_in[3];
    const float* b2 = (const float*)d_in[4];
    float* out = (float*)d_out;

    const int B = in_sizes[0] / (6 * T_STEPS);  // 1024
    snn_kernel<<<dim3(B), dim3(192), 0, stream>>>(x, W1, b1, W2, b2, out);
}